// Round 2
// baseline (1335.171 us; speedup 1.0000x reference)
//
#include <hip/hip_runtime.h>

typedef float  f32x4   __attribute__((ext_vector_type(4)));
typedef short  short8  __attribute__((ext_vector_type(8)));
typedef short  short4v __attribute__((ext_vector_type(4)));
typedef __bf16 bf16x8  __attribute__((ext_vector_type(8)));

__device__ __forceinline__ unsigned short f2bf(float f) {
    unsigned u = __builtin_bit_cast(unsigned, f);
    unsigned r = u + 0x7fffu + ((u >> 16) & 1u);   // round-to-nearest-even
    return (unsigned short)(r >> 16);
}

__device__ __forceinline__ short4v cvt4(float4 v) {
    short4v s;                                      // compiler fuses to v_cvt_pk_bf16_f32
    s.x = __builtin_bit_cast(short, (__bf16)v.x);
    s.y = __builtin_bit_cast(short, (__bf16)v.y);
    s.z = __builtin_bit_cast(short, (__bf16)v.z);
    s.w = __builtin_bit_cast(short, (__bf16)v.w);
    return s;
}

// ---------------------------------------------------------------------------
// Small GEMM:  St[n][m] = sum_k X[m][k] * W[k][n]   (K = 128 fixed)
// (unchanged from round 1 — validated, ~2% of runtime)
// ---------------------------------------------------------------------------
template<int NMAT>
__global__ __launch_bounds__(256) void k_xw_t(const float* __restrict__ X,
                                              const float* __restrict__ W,
                                              short* __restrict__ St, int M) {
    constexpr int K   = 128;
    constexpr int NPT = NMAT / 4;
    __shared__ float Xs[64][129];
    __shared__ float Ws[K][NMAT];

    const int tid = threadIdx.x;
    const int m0  = blockIdx.x * 64;

    constexpr int WCH = K * NMAT / 4 / 256;
    #pragma unroll
    for (int j = 0; j < WCH; ++j) {
        int ch = tid + j * 256;
        ((float4*)Ws)[ch] = ((const float4*)W)[ch];
    }
    #pragma unroll
    for (int j = 0; j < 8; ++j) {
        int ch = tid + j * 256;
        int r = ch >> 5, c4 = ch & 31;
        float4 v = *(const float4*)(X + (size_t)(m0 + r) * K + c4 * 4);
        Xs[r][c4 * 4 + 0] = v.x; Xs[r][c4 * 4 + 1] = v.y;
        Xs[r][c4 * 4 + 2] = v.z; Xs[r][c4 * 4 + 3] = v.w;
    }
    __syncthreads();

    const int m  = tid & 63;
    const int n0 = (tid >> 6) * NPT;
    float acc[NPT];
    #pragma unroll
    for (int i = 0; i < NPT; ++i) acc[i] = 0.f;

    for (int k = 0; k < K; ++k) {
        float x = Xs[m][k];
        #pragma unroll
        for (int i = 0; i < NPT; i += 4) {
            float4 w = *(const float4*)&Ws[k][n0 + i];
            acc[i + 0] += x * w.x; acc[i + 1] += x * w.y;
            acc[i + 2] += x * w.z; acc[i + 3] += x * w.w;
        }
    }
    #pragma unroll
    for (int i = 0; i < NPT; ++i)
        St[(size_t)(n0 + i) * M + m0 + m] = (short)f2bf(acc[i]);
}

// ---------------------------------------------------------------------------
// Streaming GEMM:  out[m][n] = sum_k adj[m][k] * S[k][n]  (+bias, opt. relu)
// BM=32 -> grid 512 (2 blocks/CU). A prefetched 4 tiles deep, B 2 deep, all
// slot indices macro-literal (no runtime reg indexing). Raw s_barrier +
// explicit lgkmcnt(0): barrier never drains vmcnt, so the 6-14 outstanding
// wave-loads per wave persist across barriers -> HBM stream never starves.
// LDS double-buffered, one barrier per K-step.
// Waves 2x2: wave tile 16 x (BN/2); 16x16x32 bf16 MFMA.
// ---------------------------------------------------------------------------
template<int BN, bool RELU>
__global__ __launch_bounds__(256) void k_adj_gemm(const float* __restrict__ A,
                                                  const short* __restrict__ Bt,
                                                  const float* __restrict__ bias,
                                                  float* __restrict__ out,
                                                  int M, int K) {
    constexpr int BM  = 32, BK = 64;
    constexpr int DA  = 4, DB = 2;            // prefetch depths
    constexpr int NF  = BN / 32;              // n-frags per wave (4 or 2)
    constexpr int ACH = BM * BK / (4 * 256);  // 2 float4 chunks / thread
    constexpr int BCH = BN * BK / (8 * 256);  // 4 or 2 uint4 chunks / thread

    __shared__ short As[2][BM][72];           // 72-short rows: bank spread
    __shared__ short Bs[2][BN][72];

    const int tid  = threadIdx.x;
    const int row0 = blockIdx.x * BM;
    const int lane = tid & 63, wave = tid >> 6;
    const int wr = wave >> 1, wc = wave & 1;
    const int lr = lane & 15, lk = lane >> 4;

    f32x4 acc[NF];
    #pragma unroll
    for (int n = 0; n < NF; ++n) acc[n] = (f32x4)0.f;

    float4 aP[DA][ACH];
    uint4  bP[DB][BCH];

    const int NT = K / BK;                    // 256

#define LOAD_A(SL, K0)                                                         \
    {                                                                          \
        _Pragma("unroll")                                                      \
        for (int j = 0; j < ACH; ++j) {                                        \
            int ch = tid + j * 256, r = ch >> 4, c4 = ch & 15;                 \
            aP[SL][j] = *(const float4*)(A + (size_t)(row0 + r) * K + (K0) + c4 * 4); \
        }                                                                      \
    }
#define LOAD_B(SL, K0)                                                         \
    {                                                                          \
        _Pragma("unroll")                                                      \
        for (int j = 0; j < BCH; ++j) {                                        \
            int ch = tid + j * 256, n = ch >> 3, c = ch & 7;                   \
            bP[SL][j] = *(const uint4*)(Bt + (size_t)n * K + (K0) + c * 8);    \
        }                                                                      \
    }

    // prologue: tiles 0..3 (A), 0..1 (B)
    LOAD_A(0, 0); LOAD_A(1, BK); LOAD_A(2, 2 * BK); LOAD_A(3, 3 * BK);
    LOAD_B(0, 0); LOAD_B(1, BK);

#define ITER(KT, SA, SB)                                                       \
    {                                                                          \
        const int kt = (KT);                                                   \
        /* write phase: fp32->bf16 cvt + LDS (compiler emits counted vmcnt) */ \
        _Pragma("unroll")                                                      \
        for (int j = 0; j < ACH; ++j) {                                        \
            int ch = tid + j * 256, r = ch >> 4, c4 = ch & 15;                 \
            *(short4v*)&As[SB][r][c4 * 4] = cvt4(aP[SA][j]);                   \
        }                                                                      \
        _Pragma("unroll")                                                      \
        for (int j = 0; j < BCH; ++j) {                                        \
            int ch = tid + j * 256, n = ch >> 3, c = ch & 7;                   \
            *(uint4*)&Bs[SB][n][c * 8] = bP[SB][j];                           \
        }                                                                      \
        /* refill just-freed slots */                                          \
        if (kt + DA < NT) LOAD_A(SA, (kt + DA) * BK);                          \
        if (kt + DB < NT) LOAD_B(SB, (kt + DB) * BK);                          \
        /* my LDS writes committed, then barrier (no vmcnt drain!) */          \
        asm volatile("s_waitcnt lgkmcnt(0)" ::: "memory");                     \
        __builtin_amdgcn_s_barrier();                                          \
        /* compute phase */                                                    \
        _Pragma("unroll")                                                      \
        for (int s = 0; s < 2; ++s) {                                          \
            short8 a = *(const short8*)((const char*)&As[SB][0][0] +           \
                        (wr * 16 + lr) * 144 + s * 64 + lk * 16);              \
            _Pragma("unroll")                                                  \
            for (int n = 0; n < NF; ++n) {                                     \
                short8 b = *(const short8*)((const char*)&Bs[SB][0][0] +       \
                        (wc * (BN / 2) + n * 16 + lr) * 144 + s * 64 + lk * 16); \
                acc[n] = __builtin_amdgcn_mfma_f32_16x16x32_bf16(              \
                    __builtin_bit_cast(bf16x8, a),                             \
                    __builtin_bit_cast(bf16x8, b), acc[n], 0, 0, 0);           \
            }                                                                  \
        }                                                                      \
    }

    for (int g = 0; g < NT / 4; ++g) {
        ITER(g * 4 + 0, 0, 0)
        ITER(g * 4 + 1, 1, 1)
        ITER(g * 4 + 2, 2, 0)
        ITER(g * 4 + 3, 3, 1)
    }
#undef ITER
#undef LOAD_A
#undef LOAD_B

    // epilogue: C/D layout col = lane&15, row = (lane>>4)*4 + j
    #pragma unroll
    for (int n = 0; n < NF; ++n) {
        int col = wc * (BN / 2) + n * 16 + lr;
        float bv = bias[col];
        #pragma unroll
        for (int j = 0; j < 4; ++j) {
            int row = row0 + wr * 16 + lk * 4 + j;
            float v = acc[n][j] + bv;
            if (RELU) v = fmaxf(v, 0.f);
            out[(size_t)row * BN + col] = v;
        }
    }
}

extern "C" void kernel_launch(void* const* d_in, const int* in_sizes, int n_in,
                              void* d_out, int out_size, void* d_ws, size_t ws_size,
                              hipStream_t stream) {
    const int N = 16384, NH1 = 128, NH2 = 64;
    const float* feature = (const float*)d_in[0];
    const float* adj     = (const float*)d_in[1];
    const float* W1      = (const float*)d_in[2];
    const float* b1      = (const float*)d_in[3];
    const float* W2      = (const float*)d_in[4];
    const float* b2      = (const float*)d_in[5];

    // workspace layout (needs 14 MiB)
    short* S1t = (short*)d_ws;                            // [128][16384] bf16, 4 MiB
    float* h   = (float*)((char*)d_ws + (4u << 20));      // [16384][128] fp32, 8 MiB
    short* S2t = (short*)((char*)d_ws + (12u << 20));     // [64][16384]  bf16, 2 MiB

    k_xw_t<NH1><<<N / 64, 256, 0, stream>>>(feature, W1, S1t, N);
    k_adj_gemm<NH1, true ><<<N / 32, 256, 0, stream>>>(adj, S1t, b1, h, N, N);
    k_xw_t<NH2><<<N / 64, 256, 0, stream>>>(h, W2, S2t, N);
    k_adj_gemm<NH2, false><<<N / 32, 256, 0, stream>>>(adj, S2t, b2, (float*)d_out, N, N);
    (void)in_sizes; (void)n_in; (void)out_size; (void)ws_size;
}

// Round 4
// 539.111 us; speedup vs baseline: 2.4766x; 2.4766x over previous
//
#include <hip/hip_runtime.h>
#include <stdint.h>

typedef float  f32x4  __attribute__((ext_vector_type(4)));
typedef short  short8 __attribute__((ext_vector_type(8)));
typedef __bf16 bf16x8 __attribute__((ext_vector_type(8)));

__device__ __forceinline__ unsigned short f2bf(float f) {
    unsigned u = __builtin_bit_cast(unsigned, f);
    unsigned r = u + 0x7fffu + ((u >> 16) & 1u);   // round-to-nearest-even
    return (unsigned short)(r >> 16);
}

__device__ __forceinline__ short8 cvt8(f32x4 a, f32x4 b) {
    short8 r;
    r[0] = (short)f2bf(a[0]); r[1] = (short)f2bf(a[1]);
    r[2] = (short)f2bf(a[2]); r[3] = (short)f2bf(a[3]);
    r[4] = (short)f2bf(b[0]); r[5] = (short)f2bf(b[1]);
    r[6] = (short)f2bf(b[2]); r[7] = (short)f2bf(b[3]);
    return r;
}

typedef const __attribute__((address_space(1))) void* gas_p;
typedef __attribute__((address_space(3))) void*       las_p;
__device__ __forceinline__ void gld_lds16(const void* g, void* l) {
    __builtin_amdgcn_global_load_lds((gas_p)g, (las_p)l, 16, 0, 0);
}

__device__ __forceinline__ f32x4 mfma16(short8 a, short8 b, f32x4 c) {
    return __builtin_amdgcn_mfma_f32_16x16x32_bf16(
        __builtin_bit_cast(bf16x8, a), __builtin_bit_cast(bf16x8, b), c, 0, 0, 0);
}

// ---------------------------------------------------------------------------
// Small GEMM:  St[n][m] = sum_k X[m][k] * W[k][n]   (K = 128 fixed)
// (unchanged — validated, ~2% of runtime)
// ---------------------------------------------------------------------------
template<int NMAT>
__global__ __launch_bounds__(256) void k_xw_t(const float* __restrict__ X,
                                              const float* __restrict__ W,
                                              short* __restrict__ St, int M) {
    constexpr int K   = 128;
    constexpr int NPT = NMAT / 4;
    __shared__ float Xs[64][129];
    __shared__ float Ws[K][NMAT];

    const int tid = threadIdx.x;
    const int m0  = blockIdx.x * 64;

    constexpr int WCH = K * NMAT / 4 / 256;
    #pragma unroll
    for (int j = 0; j < WCH; ++j) {
        int ch = tid + j * 256;
        ((float4*)Ws)[ch] = ((const float4*)W)[ch];
    }
    #pragma unroll
    for (int j = 0; j < 8; ++j) {
        int ch = tid + j * 256;
        int r = ch >> 5, c4 = ch & 31;
        float4 v = *(const float4*)(X + (size_t)(m0 + r) * K + c4 * 4);
        Xs[r][c4 * 4 + 0] = v.x; Xs[r][c4 * 4 + 1] = v.y;
        Xs[r][c4 * 4 + 2] = v.z; Xs[r][c4 * 4 + 3] = v.w;
    }
    __syncthreads();

    const int m  = tid & 63;
    const int n0 = (tid >> 6) * NPT;
    float acc[NPT];
    #pragma unroll
    for (int i = 0; i < NPT; ++i) acc[i] = 0.f;

    for (int k = 0; k < K; ++k) {
        float x = Xs[m][k];
        #pragma unroll
        for (int i = 0; i < NPT; i += 4) {
            float4 w = *(const float4*)&Ws[k][n0 + i];
            acc[i + 0] += x * w.x; acc[i + 1] += x * w.y;
            acc[i + 2] += x * w.z; acc[i + 3] += x * w.w;
        }
    }
    #pragma unroll
    for (int i = 0; i < NPT; ++i)
        St[(size_t)(n0 + i) * M + m0 + m] = (short)f2bf(acc[i]);
}

// ---------------------------------------------------------------------------
// Streaming GEMM:  out[m][n] = sum_k adj[m][k] * S[k][n]  (+bias, opt. relu)
//  - BM=32, 128 threads (2 waves x 16 rows), grid 512 -> 2 blocks/CU.
//  - A: wave-private, global->reg dwordx4, 2 tiles deep (32 VGPR), cvt in reg.
//    adj read exactly once grid-wide; A never in LDS.
//  - B: global_load_lds DMA, double-buffered, pre-swizzled source
//    (XOR (row&7)<<4, linear LDS dest) -> conflict-free ds_read_b128.
//  - Counted vmcnt (never 0) + raw s_barrier + sched_barrier(0) pinning:
//    loads stay in flight across barriers. Clamped tail keeps counts uniform.
//  - Prologue order A(0), B(0), A(1): B(0) is followed by exactly 4 A-loads,
//    so vmcnt(BCH+8) is exact for ITER(0) too (steady-state-identical).
// ---------------------------------------------------------------------------
template<int BN, bool RELU>
__global__ __launch_bounds__(128, 1) void k_adj_gemm(const float* __restrict__ A,
                                                     const short* __restrict__ Bt,
                                                     const float* __restrict__ bias,
                                                     float* __restrict__ out,
                                                     int M, int K) {
    constexpr int BM    = 32, BK = 64;
    constexpr int NF    = BN / 16;               // n-frags per wave (8 or 4)
    constexpr int BTILE = BN * BK * 2;           // B tile bytes (16384 or 8192)
    constexpr int BCH   = BTILE / (128 * 16);    // DMA instrs per thread (8 or 4)
    constexpr int VMCNT = BCH + 8;               // ops after B(t): A(t+1)x4 + B(t+1) + A(t+2)x4

    __shared__ short Bs[2][BN * 64];

    const int tid  = threadIdx.x;
    const int wave = tid >> 6, lane = tid & 63;
    const int lr   = lane & 15, lk = lane >> 4;
    const int row_g = blockIdx.x * BM + wave * 16 + lr;

    const char* Abase = (const char*)A + (size_t)row_g * K * 4 + lk * 32;

    // swizzled per-lane LDS read offsets for B frags (s=0,1)
    const int offs0 = (lk * 16)        ^ ((lr & 7) << 4);
    const int offs1 = (64 + lk * 16)   ^ ((lr & 7) << 4);

    f32x4 acc[NF];
    #pragma unroll
    for (int n = 0; n < NF; ++n) acc[n] = (f32x4)0.f;

    f32x4 a0[4], a1[4];                          // A prefetch slots, 2 tiles deep
    const int NT = K / BK;                       // 256

#define STAGE_B(BUF, KT)                                                        \
    {                                                                           \
        _Pragma("unroll")                                                       \
        for (int j = 0; j < BCH; ++j) {                                         \
            int o = (tid + j * 128) * 16;        /* linear byte off in tile */  \
            int r = o >> 7, w = o & 127;                                        \
            const char* src = (const char*)Bt + (size_t)r * (K * 2)             \
                              + (size_t)(KT) * 128 + (w ^ ((r & 7) << 4));      \
            gld_lds16(src, (char*)&Bs[BUF][0] + o);                             \
        }                                                                       \
    }

#define LOAD_A(SLOT, KT)                                                        \
    {                                                                           \
        const char* p = Abase + (size_t)(KT) * 256;                             \
        SLOT[0] = *(const f32x4*)(p);                                           \
        SLOT[1] = *(const f32x4*)(p + 16);                                      \
        SLOT[2] = *(const f32x4*)(p + 128);                                     \
        SLOT[3] = *(const f32x4*)(p + 144);                                     \
    }

    // prologue (order matters for vmcnt accounting — see header comment)
    LOAD_A(a0, 0)
    STAGE_B(0, 0)
    LOAD_A(a1, 1)

#define ITER(KT, SA, CUR, NXT)                                                  \
    {                                                                           \
        /* P1: stage B(kt+1) into NXT (clamped at tail, count-uniform) */       \
        { int ktn = (KT) + 1 < NT ? (KT) + 1 : NT - 1; STAGE_B(NXT, ktn) }      \
        __builtin_amdgcn_sched_barrier(0);                                      \
        /* P2a: cvt A(kt) -> bf16 frags (compiler inserts its own vmcnt) */     \
        short8 fa0 = cvt8(SA[0], SA[1]);                                        \
        short8 fa1 = cvt8(SA[2], SA[3]);                                        \
        /* P2b: refill slot with A(kt+2) */                                     \
        { int kta = (KT) + 2 < NT ? (KT) + 2 : NT - 1; LOAD_A(SA, kta) }        \
        __builtin_amdgcn_sched_barrier(0);                                      \
        /* P3: B(kt) landed; newer loads stay in flight */                      \
        asm volatile("s_waitcnt vmcnt(%0)" :: "i"(VMCNT) : "memory");           \
        __builtin_amdgcn_s_barrier();                                           \
        __builtin_amdgcn_sched_barrier(0);                                      \
        /* P4: MFMA over n-frags, both K-halves */                              \
        _Pragma("unroll")                                                       \
        for (int n = 0; n < NF; ++n) {                                          \
            short8 b0 = *(const short8*)((const char*)&Bs[CUR][0]               \
                                         + n * 2048 + lr * 128 + offs0);        \
            acc[n] = mfma16(fa0, b0, acc[n]);                                   \
            short8 b1 = *(const short8*)((const char*)&Bs[CUR][0]               \
                                         + n * 2048 + lr * 128 + offs1);        \
            acc[n] = mfma16(fa1, b1, acc[n]);                                   \
        }                                                                       \
        __builtin_amdgcn_sched_barrier(0);                                      \
        __builtin_amdgcn_s_barrier();  /* CUR free for next iter's DMA */       \
    }

    for (int g = 0; g < NT / 2; ++g) {
        ITER(2 * g,     a0, 0, 1)
        ITER(2 * g + 1, a1, 1, 0)
    }
#undef ITER
#undef LOAD_A
#undef STAGE_B

    // epilogue: D layout col = lane&15, row = (lane>>4)*4 + j  [m89-verified]
    #pragma unroll
    for (int n = 0; n < NF; ++n) {
        int col = n * 16 + lr;
        float bv = bias[col];
        #pragma unroll
        for (int j = 0; j < 4; ++j) {
            int row = blockIdx.x * BM + wave * 16 + lk * 4 + j;
            float v = acc[n][j] + bv;
            if (RELU) v = fmaxf(v, 0.f);
            out[(size_t)row * BN + col] = v;
        }
    }
}

extern "C" void kernel_launch(void* const* d_in, const int* in_sizes, int n_in,
                              void* d_out, int out_size, void* d_ws, size_t ws_size,
                              hipStream_t stream) {
    const int N = 16384, NH1 = 128, NH2 = 64;
    const float* feature = (const float*)d_in[0];
    const float* adj     = (const float*)d_in[1];
    const float* W1      = (const float*)d_in[2];
    const float* b1      = (const float*)d_in[3];
    const float* W2      = (const float*)d_in[4];
    const float* b2      = (const float*)d_in[5];

    short* S1t = (short*)d_ws;                            // [128][16384] bf16, 4 MiB
    float* h   = (float*)((char*)d_ws + (4u << 20));      // [16384][128] fp32, 8 MiB
    short* S2t = (short*)((char*)d_ws + (12u << 20));     // [64][16384]  bf16, 2 MiB

    k_xw_t<NH1><<<N / 64, 256, 0, stream>>>(feature, W1, S1t, N);
    k_adj_gemm<NH1, true ><<<N / 32, 128, 0, stream>>>(adj, S1t, b1, h, N, N);
    k_xw_t<NH2><<<N / 64, 256, 0, stream>>>(h, W2, S2t, N);
    k_adj_gemm<NH2, false><<<N / 32, 128, 0, stream>>>(adj, S2t, b2, (float*)d_out, N, N);
    (void)in_sizes; (void)n_in; (void)out_size; (void)ws_size;
}